// Round 1
// 306.192 us; speedup vs baseline: 1.0084x; 1.0084x over previous
//
#include <hip/hip_runtime.h>
#include <hip/hip_bf16.h>
#include <math.h>

#define Bsz 64
#define T 32
#define H 768
#define E 8
#define NB 2
#define DFF 3072
#define NBEAM (Bsz * NB)   // 128
#define NT4MAX 40

// d_out layout (floats):
#define OUT_BS 3145728
#define OUT_ER 3145856
#define OUT_BI 3145984
#define OUT_IL 3146112

// ws layout (float units):
#define WS_LOGITS 0                 // 3*512 chunked partial logits
#define WS_BEAMW  1536              // 128
#define WS_SORT   1664              // 128 int
#define WS_T4E    1792              // 40 int
#define WS_T4B    1832              // 40 int
#define WS_T4C    1872              // 40 int
#define WS_XBF    2048              // x bf16: 786432 floats
#define WS_HBF    (2048 + 786432)   // h bf16: 6291456 floats

typedef __attribute__((ext_vector_type(8))) short short8;
typedef __attribute__((ext_vector_type(4))) float f32x4;

__device__ __forceinline__ short8 cvt8(const float4 u, const float4 v) {
    union { short8 s; unsigned w[4]; } r;
    __hip_bfloat162 t;
    t = __float22bfloat162_rn(make_float2(u.x, u.y)); r.w[0] = *(unsigned*)&t;
    t = __float22bfloat162_rn(make_float2(u.z, u.w)); r.w[1] = *(unsigned*)&t;
    t = __float22bfloat162_rn(make_float2(v.x, v.y)); r.w[2] = *(unsigned*)&t;
    t = __float22bfloat162_rn(make_float2(v.z, v.w)); r.w[3] = *(unsigned*)&t;
    return r.s;
}

// async 16B global -> LDS (dest = uniform base + lane*16)
__device__ __forceinline__ void async16(void* lds, const void* g) {
    __builtin_amdgcn_global_load_lds(
        (const __attribute__((address_space(1))) void*)g,
        (__attribute__((address_space(3))) void*)lds, 16, 0, 0);
}

// ---------------------------------------------------------------------------
// x fp32 -> bf16, fully coalesced. 1536 blocks.
// ---------------------------------------------------------------------------
__global__ __launch_bounds__(256) void conv_x_kernel(
    const float* __restrict__ x, ushort* __restrict__ xb, int n4)
{
    const int i = blockIdx.x * 256 + threadIdx.x;
    if (i >= n4) return;
    const float4 v = ((const float4*)x)[i];
    __hip_bfloat162 t0 = __float22bfloat162_rn(make_float2(v.x, v.y));
    __hip_bfloat162 t1 = __float22bfloat162_rn(make_float2(v.z, v.w));
    ushort4 o;
    o.x = (*(unsigned*)&t0) & 0xffff; o.y = (*(unsigned*)&t0) >> 16;
    o.z = (*(unsigned*)&t1) & 0xffff; o.w = (*(unsigned*)&t1) >> 16;
    ((ushort4*)xb)[i] = o;
}

// ---------------------------------------------------------------------------
// Gate partial logits: grid (3 chunks, 64 batches). Block handles 256 cols:
// column mean over T, dot with gate_w chunk for all 8 experts. Deterministic
// (no atomics): writes logits_part[chunk][b][e].
// ---------------------------------------------------------------------------
__global__ __launch_bounds__(256) void gate_partial_kernel(
    const float* __restrict__ x, const float* __restrict__ gate_w,
    float* __restrict__ logits_part)
{
    __shared__ float part[4][E];
    const int chunk = blockIdx.x, b = blockIdx.y;
    const int tid = threadIdx.x, wv = tid >> 6, lane = tid & 63;
    const int c = chunk * 256 + tid;
    const float* xp = x + (size_t)b * T * H + c;
    float s = 0.f;
    #pragma unroll
    for (int t = 0; t < T; ++t) s += xp[t * H];
    const float avg = s * (1.0f / T);
    #pragma unroll
    for (int e = 0; e < E; ++e) {
        float p = avg * gate_w[e * H + c];
        #pragma unroll
        for (int off = 32; off; off >>= 1) p += __shfl_down(p, off, 64);
        if (lane == 0) part[wv][e] = p;
    }
    __syncthreads();
    if (tid < E) {
        float t = part[0][tid] + part[1][tid] + part[2][tid] + part[3][tid];
        logits_part[chunk * 512 + b * E + tid] = t;
    }
}

// ---------------------------------------------------------------------------
// Gating: softmax, top-2, outputs, importance loss, expert tables.
// 1 block, 64 threads, FULLY parallel (ballot/popcount sort, shfl reduce).
// ---------------------------------------------------------------------------
__global__ __launch_bounds__(64) void gating_kernel(
    const float* __restrict__ logits_part, float* __restrict__ beam_w,
    int* __restrict__ sortb, int* __restrict__ t4e, int* __restrict__ t4b,
    int* __restrict__ t4c, float* __restrict__ dout)
{
    const int r = threadIdx.x;  // batch row 0..63
    float v[E];
    float mx = -1e30f;
    #pragma unroll
    for (int e = 0; e < E; ++e) {
        v[e] = logits_part[r * E + e] + logits_part[512 + r * E + e]
             + logits_part[1024 + r * E + e];
        mx = fmaxf(mx, v[e]);
    }
    float s = 0.f;
    #pragma unroll
    for (int e = 0; e < E; ++e) { v[e] = expf(v[e] - mx); s += v[e]; }
    const float inv = 1.0f / s;
    #pragma unroll
    for (int e = 0; e < E; ++e) v[e] *= inv;
    // top-2 (stable: lower index wins ties, matches jax.lax.top_k)
    float v0 = -1.f, v1 = -1.f; int i0 = 0, i1 = 0;
    #pragma unroll
    for (int e = 0; e < E; ++e) {
        if (v[e] > v0)      { v1 = v0; i1 = i0; v0 = v[e]; i0 = e; }
        else if (v[e] > v1) { v1 = v[e]; i1 = e; }
    }
    const int b0 = 2 * r, b1 = 2 * r + 1;
    dout[OUT_BS + b0] = v0;          dout[OUT_BS + b1] = v1;
    dout[OUT_ER + b0] = (float)i0;   dout[OUT_ER + b1] = (float)i1;
    dout[OUT_BI + b0] = (float)b0;   dout[OUT_BI + b1] = (float)b1;
    beam_w[b0] = v0;  beam_w[b1] = v1;
    // importance loss via 64-lane butterfly reductions
    float imp[E];
    #pragma unroll
    for (int e = 0; e < E; ++e) {
        float t = v[e];
        #pragma unroll
        for (int off = 1; off < 64; off <<= 1) t += __shfl_xor(t, off, 64);
        imp[e] = t;
    }
    if (r == 0) {
        float tot = 0.f;
        #pragma unroll
        for (int e = 0; e < E; ++e) tot += imp[e];
        const float mean = tot / E;
        float var = 0.f;
        #pragma unroll
        for (int e = 0; e < E; ++e) { float d = imp[e] - mean; var += d * d; }
        var /= (E - 1);
        dout[OUT_IL] = var / (mean * mean);
    }
    // expert-grouped sort via ballots (beams 2r even-mask, 2r+1 odd-mask)
    unsigned long long m0[E], m1[E];
    #pragma unroll
    for (int e = 0; e < E; ++e) {
        m0[e] = __ballot(i0 == e);
        m1[e] = __ballot(i1 == e);
    }
    int cnt[E], off[E];
    int a0 = 0;
    #pragma unroll
    for (int e = 0; e < E; ++e) {
        cnt[e] = __popcll(m0[e]) + __popcll(m1[e]);
        off[e] = a0; a0 += cnt[e];
    }
    const unsigned long long below = (r == 0) ? 0ull : ((1ull << r) - 1ull);
    const unsigned long long incl  = below | (1ull << r);
    const int pos0 = __popcll(m0[i0] & below) + __popcll(m1[i0] & below);
    const int pos1 = __popcll(m0[i1] & incl)  + __popcll(m1[i1] & below);
    sortb[off[i0] + pos0] = b0;
    sortb[off[i1] + pos1] = b1;
    // 4-beam tile table
    int tb[E]; int tc = 0;
    #pragma unroll
    for (int e = 0; e < E; ++e) { tb[e] = tc; tc += (cnt[e] + 3) >> 2; }
    if (r < E) {
        const int e = r;
        int j = tb[e];
        for (int i = 0; i < cnt[e]; i += 4, ++j) {
            t4e[j] = e;
            t4b[j] = off[e] + i;
            t4c[j] = (cnt[e] - i < 4) ? (cnt[e] - i) : 4;
        }
    }
    for (int t = tc + r; t < NT4MAX; t += 64) t4c[t] = 0;
}

// ---------------------------------------------------------------------------
// LDS double-buffered MFMA GEMM, single barrier per k-tile.
// Tile: 128(m: 4 beams of one expert) x NTILE(n), Ktile=64.
// 4 waves in 2x2; wave tile 64m x NTILE/2 n.
// A: bf16 via async global_load_lds (src-side XOR swizzle).
// W: fp32 -> reg prefetch -> cvt bf16 -> swizzled ds_write.
// Pipeline per ktile: cvt+write W(kt) | barrier | issue A-DMA(kt+1)+load
// W(kt+1) into OTHER buffer | compute(kt).  Barrier's vmcnt(0) catches the
// DMA issued one compute-phase earlier -> latency hidden.
//
// XCD-chunked block swizzle (T1): the ~4 m-group tiles of one
// (expert, n-strip) share a W panel (NTILE x KTOT fp32). Logical order is
// lid = strip*NT4MAX + tile (tiles fastest, expert-major), and
// lid = (hw%8)*q + hw/8 pins each contiguous logical chunk to one XCD so
// the W-sharing peers are co-resident on the same 4 MiB L2: first peer
// misses to HBM, the other ~3 hit L2. W HBM traffic -> ~once per GEMM,
// and the re-read latency (~200cy L2) now fits inside the one-compute-
// phase window that the __syncthreads vmcnt(0) drain allows.
// Requires nwg % 8 == 0 (24*40=960, 12*40=480: both OK).
// ---------------------------------------------------------------------------
template <int KTOT, int NTILE, bool DO_GELU>
__global__ __launch_bounds__(256, 2) void moe_ffn_mfma(
    const ushort* __restrict__ Abf, int a_div,
    const float* __restrict__ Wf32, int w_rows,
    const float* __restrict__ biasb,
    const int* __restrict__ sortb, const int* __restrict__ t4e,
    const int* __restrict__ t4b, const int* __restrict__ t4c,
    const float* __restrict__ beam_w,
    void* __restrict__ Obase)
{
    constexpr int KT = KTOT / 64;
    constexpr int WF = NTILE / 32;      // n-frags per wave / W slots per thread
    __shared__ __align__(16) ushort sA[2][128 * 64];
    __shared__ __align__(16) ushort sB[2][NTILE * 64];

    // --- XCD-chunked bijective swizzle (nwg % 8 == 0 for both launches) ---
    const int nx  = gridDim.x;
    const int nwg = nx * NT4MAX;
    const int hw  = blockIdx.y * nx + blockIdx.x;
    const int q8  = nwg >> 3;
    const int lid = (hw & 7) * q8 + (hw >> 3);
    const int tile  = lid % NT4MAX;     // m-group (expert-major, W-sharing)
    const int strip = lid / NT4MAX;     // n-strip

    const int cnt  = t4c[tile];
    if (cnt == 0) return;
    const int e    = t4e[tile];
    const int base = t4b[tile];
    const int tid  = threadIdx.x;
    const int wv   = tid >> 6;
    const int lane = tid & 63;
    const int quad = lane >> 4;
    const int l16  = lane & 15;
    const int mh   = (wv & 1) * 64;
    const int nh   = (wv >> 1) * (NTILE / 2);
    const int n0   = strip * NTILE;

    int bm[4];
    #pragma unroll
    for (int s = 0; s < 4; ++s) bm[s] = sortb[base + (s < cnt ? s : cnt - 1)];

    // A DMA sources: wave does slots j=wv*4+jj; slot s=j*64+lane:
    // row=s>>3, pos=s&7, source chunk c = pos^(row&7)
    const ushort* aseg[4];
    #pragma unroll
    for (int jj = 0; jj < 4; ++jj) {
        const int s = (wv * 4 + jj) * 64 + lane;
        const int r = s >> 3;
        const int c = (s & 7) ^ (r & 7);
        aseg[jj] = Abf + (size_t)(bm[r >> 5] / a_div) * T * KTOT
                 + (size_t)(r & 31) * KTOT + c * 8;
    }
    // W slots: s=jj*256+tid: row=s>>3, c=(s&7)^(row&7)
    const float* wseg[WF];
    int wslot[WF];
    #pragma unroll
    for (int jj = 0; jj < WF; ++jj) {
        const int s = jj * 256 + tid;
        const int r = s >> 3;
        const int c = (s & 7) ^ (r & 7);
        wseg[jj] = Wf32 + (size_t)e * w_rows * KTOT + (size_t)(n0 + r) * KTOT + c * 8;
        wslot[jj] = s * 8;
    }

    int arow[4], ar7[4], brow[WF], br7[WF];
    #pragma unroll
    for (int mt = 0; mt < 4; ++mt) {
        const int r = mh + mt * 16 + l16;
        arow[mt] = r * 64; ar7[mt] = r & 7;
    }
    #pragma unroll
    for (int nt = 0; nt < WF; ++nt) {
        const int r = nh + nt * 16 + l16;
        brow[nt] = r * 64; br7[nt] = r & 7;
    }

    // prologue: tile 0 in flight
    float4 wr[WF][2];
    #pragma unroll
    for (int jj = 0; jj < WF; ++jj) {
        wr[jj][0] = *(const float4*)(wseg[jj]);
        wr[jj][1] = *(const float4*)(wseg[jj] + 4);
    }
    #pragma unroll
    for (int jj = 0; jj < 4; ++jj)
        async16((char*)sA[0] + (wv * 4 + jj) * 1024, aseg[jj]);

    f32x4 acc[4][WF];
    #pragma unroll
    for (int mt = 0; mt < 4; ++mt)
        #pragma unroll
        for (int nt = 0; nt < WF; ++nt) acc[mt][nt] = {0.f, 0.f, 0.f, 0.f};

    for (int kt = 0; kt < KT; ++kt) {
        const int p = kt & 1;
        // stage W(kt) into LDS (waits its global loads via dependency)
        #pragma unroll
        for (int jj = 0; jj < WF; ++jj)
            *(short8*)(sB[p] + wslot[jj]) = cvt8(wr[jj][0], wr[jj][1]);
        __syncthreads();   // drains A-DMA(kt) + publishes W(kt)
        if (kt + 1 < KT) { // prefetch NEXT tile into other buffer (hidden by compute)
            const int kn = (kt + 1) * 64;
            #pragma unroll
            for (int jj = 0; jj < 4; ++jj)
                async16((char*)sA[1 - p] + (wv * 4 + jj) * 1024, aseg[jj] + kn);
            #pragma unroll
            for (int jj = 0; jj < WF; ++jj) {
                wr[jj][0] = *(const float4*)(wseg[jj] + kn);
                wr[jj][1] = *(const float4*)(wseg[jj] + kn + 4);
            }
        }
        // compute(kt)
        #pragma unroll
        for (int ks = 0; ks < 2; ++ks) {
            short8 af[4], wf[WF];
            #pragma unroll
            for (int mt = 0; mt < 4; ++mt)
                af[mt] = *(const short8*)(sA[p] + arow[mt] + (((ks * 4 + quad) ^ ar7[mt]) * 8));
            #pragma unroll
            for (int nt = 0; nt < WF; ++nt)
                wf[nt] = *(const short8*)(sB[p] + brow[nt] + (((ks * 4 + quad) ^ br7[nt]) * 8));
            #pragma unroll
            for (int mt = 0; mt < 4; ++mt)
                #pragma unroll
                for (int nt = 0; nt < WF; ++nt)
                    acc[mt][nt] = __builtin_amdgcn_mfma_f32_16x16x32_bf16(
                        af[mt], wf[nt], acc[mt][nt], 0, 0, 0);
        }
    }

    // epilogue
    #pragma unroll
    for (int nt = 0; nt < WF; ++nt) {
        const int n = n0 + nh + nt * 16 + l16;
        const float bias = biasb[(size_t)e * w_rows + n];
        #pragma unroll
        for (int mt = 0; mt < 4; ++mt) {
            const int rowb = mh + mt * 16 + quad * 4;
            const int s = rowb >> 5;
            if (s >= cnt) continue;
            const int b = bm[s];
            const float scale = DO_GELU ? 1.0f : beam_w[b];
            #pragma unroll
            for (int r = 0; r < 4; ++r) {
                const int t = (rowb + r) & 31;
                float vv = acc[mt][nt][r] + bias;
                const size_t idx = (size_t)b * T * w_rows + (size_t)t * w_rows + n;
                if (DO_GELU) {
                    vv = 0.5f * vv * (1.0f + erff(vv * 0.70710678118654752f));
                    ((__hip_bfloat16*)Obase)[idx] = __float2bfloat16(vv);
                } else {
                    ((float*)Obase)[idx] = vv * scale;
                }
            }
        }
    }
}

extern "C" void kernel_launch(void* const* d_in, const int* in_sizes, int n_in,
                              void* d_out, int out_size, void* d_ws, size_t ws_size,
                              hipStream_t stream)
{
    const float* x      = (const float*)d_in[0];
    const float* gate_w = (const float*)d_in[1];
    const float* w1     = (const float*)d_in[2];
    const float* b1     = (const float*)d_in[3];
    const float* w2     = (const float*)d_in[4];
    const float* b2     = (const float*)d_in[5];
    float* out = (float*)d_out;
    float* ws  = (float*)d_ws;

    float*  logits = ws + WS_LOGITS;
    float*  beam_w = ws + WS_BEAMW;
    int*    sortb  = (int*)(ws + WS_SORT);
    int*    t4e    = (int*)(ws + WS_T4E);
    int*    t4b    = (int*)(ws + WS_T4B);
    int*    t4c    = (int*)(ws + WS_T4C);
    ushort* x_bf   = (ushort*)(ws + WS_XBF);
    ushort* h_bf   = (ushort*)(ws + WS_HBF);

    conv_x_kernel<<<(Bsz * T * H / 4 + 255) / 256, 256, 0, stream>>>(
        x, x_bf, Bsz * T * H / 4);
    gate_partial_kernel<<<dim3(3, Bsz), 256, 0, stream>>>(x, gate_w, logits);
    gating_kernel<<<1, 64, 0, stream>>>(logits, beam_w, sortb, t4e, t4b, t4c, out);
    // GEMM1 + GELU: M=128/tile, N=DFF in 128-strips, K=768
    moe_ffn_mfma<H, 128, true><<<dim3(DFF / 128, NT4MAX), 256, 0, stream>>>(
        x_bf, NB, w1, DFF, b1, sortb, t4e, t4b, t4c, beam_w, (void*)h_bf);
    // GEMM2 + scale: M=128/tile, N=H in 64-strips, K=3072
    moe_ffn_mfma<DFF, 64, false><<<dim3(H / 64, NT4MAX), 256, 0, stream>>>(
        h_bf, 1, w2, H, b2, sortb, t4e, t4b, t4c, beam_w, out);
}